// Round 1
// baseline (1550.812 us; speedup 1.0000x reference)
//
#include <hip/hip_runtime.h>
#include <hip/hip_bf16.h>
#include <stdint.h>

typedef short bf16x8 __attribute__((ext_vector_type(8)));
typedef float f32x4  __attribute__((ext_vector_type(4)));
typedef unsigned short u16;

#define T_TOK 4096
#define D_DIM 1024
#define I_DIM 4096
#define NE    9      // 8 routed experts + 1 shared "expert"

__device__ __forceinline__ u16 f2bf(float f) {
    union { float f; uint32_t u; } v; v.f = f;
    uint32_t u = v.u;
    u += 0x7FFFu + ((u >> 16) & 1u);   // round-to-nearest-even
    return (u16)(u >> 16);
}

__device__ __forceinline__ float gelu_tanh(float v) {
    float c = 0.7978845608028654f * (v + 0.044715f * v * v * v);
    return 0.5f * v * (1.0f + tanhf(c));
}

// ---------------------------------------------------------------- init
__global__ void k_init(int* counts) {
    int i = threadIdx.x;
    if (i < 16) counts[i] = (i == 8) ? T_TOK : 0;
}

// ---------------------------------------------------------------- router
__global__ __launch_bounds__(256) void k_router(
    const float* __restrict__ x, const float* __restrict__ gw,
    const float* __restrict__ gb,
    int* counts, int* lists, int* tok_e, int* tok_pos, float* tok_w)
{
    int wave = threadIdx.x >> 6, lane = threadIdx.x & 63;
    int t = blockIdx.x * 4 + wave;
    const float* xr = x + (size_t)t * D_DIM;

    float a[8];
#pragma unroll
    for (int e = 0; e < 8; ++e) a[e] = 0.f;
#pragma unroll
    for (int j = 0; j < D_DIM / 64; ++j) {
        int d = lane + 64 * j;
        float xv = xr[d];
        const float4* g = (const float4*)(gw + (size_t)d * 8);
        float4 g0 = g[0], g1 = g[1];
        a[0] += xv * g0.x; a[1] += xv * g0.y; a[2] += xv * g0.z; a[3] += xv * g0.w;
        a[4] += xv * g1.x; a[5] += xv * g1.y; a[6] += xv * g1.z; a[7] += xv * g1.w;
    }
#pragma unroll
    for (int off = 32; off >= 1; off >>= 1)
#pragma unroll
        for (int e = 0; e < 8; ++e) a[e] += __shfl_xor(a[e], off);

    float l[8];
#pragma unroll
    for (int e = 0; e < 8; ++e) l[e] = a[e] + gb[e];
    float mx = l[0];
#pragma unroll
    for (int e = 1; e < 8; ++e) mx = fmaxf(mx, l[e]);
    float p[8], Z = 0.f;
#pragma unroll
    for (int e = 0; e < 8; ++e) { p[e] = expf(l[e] - mx); Z += p[e]; }
#pragma unroll
    for (int e = 0; e < 8; ++e) p[e] /= Z;

    // top-2, ties -> lowest index first (matches jax.lax.top_k)
    int e0 = 0; float v0 = p[0];
#pragma unroll
    for (int e = 1; e < 8; ++e) if (p[e] > v0) { v0 = p[e]; e0 = e; }
    int e1 = -1; float v1 = -1.f;
#pragma unroll
    for (int e = 0; e < 8; ++e) if (e != e0 && p[e] > v1) { v1 = p[e]; e1 = e; }
    float denom = v0 + v1 + 1e-9f;
    float w0 = v0 / denom, w1 = v1 / denom;

    if (lane == 0) {
        int p0 = atomicAdd(&counts[e0], 1);
        int p1 = atomicAdd(&counts[e1], 1);
        lists[e0 * T_TOK + p0] = t;
        lists[e1 * T_TOK + p1] = t;
        lists[8 * T_TOK + t] = t;        // shared expert: identity
        tok_e[2 * t] = e0;  tok_e[2 * t + 1] = e1;
        tok_pos[2 * t] = p0; tok_pos[2 * t + 1] = p1;
        tok_w[2 * t] = w0;  tok_w[2 * t + 1] = w1;
    }
}

// ---------------------------------------------------------------- prefix
__global__ void k_prefix(const int* counts, int* offsets) {
    if (threadIdx.x == 0) {
        int o = 0;
        for (int e = 0; e < NE; ++e) { offsets[e] = o; o += counts[e]; }
        offsets[NE] = o;
    }
}

// ---------------------------------------------------------------- grouped GEMM
// Tile 128x128x32, 4 waves (2x2), mfma_f32_16x16x32_bf16, 4x4 frags/wave.
// A_F32: A is gathered f32 rows (x via lists); else bf16 H rows (contiguous).
// EPI 0: h = gelu(acc+bias) -> bf16 H.   EPI 1: acc+bias -> f32 P.
template <bool A_F32, int EPI>
__global__ __launch_bounds__(256)
void k_gemm(const void* __restrict__ Ag, int lda,
            const float* __restrict__ Be, const float* __restrict__ Bsh,
            const float* __restrict__ be, const float* __restrict__ bsh, int bstride,
            const int* __restrict__ counts, const int* __restrict__ offsets,
            const int* __restrict__ lists,
            void* __restrict__ Cg, int K, int N)
{
    int e  = blockIdx.x >> 5;
    int mt = blockIdx.x & 31;
    int nt = blockIdx.y;
    int cnt = counts[e];
    if (mt * 128 >= cnt) return;

    const float* B    = (e == 8) ? Bsh : (Be + (size_t)e * K * N);
    const float* bias = (e == 8) ? bsh : (be + (size_t)e * bstride);
    int off = offsets[e];
    const int* list = lists + e * T_TOK;

    __shared__ u16 As[128 * 40];   // [m][k], +8 pad
    __shared__ u16 Bs[128 * 40];   // [n][k], +8 pad

    int tid = threadIdx.x;
    int wave = tid >> 6, lane = tid & 63;
    int wr = wave >> 1, wc = wave & 1;
    int lrow = lane & 15, lk = (lane >> 4) * 8;

    f32x4 zero = {0.f, 0.f, 0.f, 0.f};
    f32x4 acc[4][4];
#pragma unroll
    for (int m = 0; m < 4; ++m)
#pragma unroll
        for (int n = 0; n < 4; ++n) acc[m][n] = zero;

    // A staging geometry: thread -> (row, 16-elem half)
    int amr = tid >> 1;
    int ahalf = tid & 1;
    int arow = mt * 128 + amr;
    int aclamp = (arow < cnt) ? arow : (cnt - 1);
    size_t asrow = A_F32 ? (size_t)list[aclamp] : (size_t)(off + aclamp);
    const float* af32 = (const float*)Ag + asrow * (size_t)lda;
    const u16*   abf  = (const u16*)Ag + asrow * (size_t)lda;

    // B staging geometry: thread -> (n pair, k group of 8)
    int bp = tid & 63;
    int br = tid >> 6;

    int nk = K >> 5;
    for (int kt = 0; kt < nk; ++kt) {
        // ---- stage A tile (128 x 32)
        {
            int kbase = kt * 32 + ahalf * 16;
            u16 tmp[16];
            if constexpr (A_F32) {
                const float4* s = (const float4*)(af32 + kbase);
                float4 v0 = s[0], v1 = s[1], v2 = s[2], v3 = s[3];
                tmp[0] = f2bf(v0.x); tmp[1] = f2bf(v0.y); tmp[2] = f2bf(v0.z); tmp[3] = f2bf(v0.w);
                tmp[4] = f2bf(v1.x); tmp[5] = f2bf(v1.y); tmp[6] = f2bf(v1.z); tmp[7] = f2bf(v1.w);
                tmp[8] = f2bf(v2.x); tmp[9] = f2bf(v2.y); tmp[10] = f2bf(v2.z); tmp[11] = f2bf(v2.w);
                tmp[12] = f2bf(v3.x); tmp[13] = f2bf(v3.y); tmp[14] = f2bf(v3.z); tmp[15] = f2bf(v3.w);
            } else {
                const bf16x8* s = (const bf16x8*)(abf + kbase);
                *(bf16x8*)&tmp[0] = s[0];
                *(bf16x8*)&tmp[8] = s[1];
            }
            *(bf16x8*)&As[amr * 40 + ahalf * 16]     = *(bf16x8*)&tmp[0];
            *(bf16x8*)&As[amr * 40 + ahalf * 16 + 8] = *(bf16x8*)&tmp[8];
        }
        // ---- stage B tile (32 x 128) -> Bs[n][k]
        {
            const float* s = B + (size_t)(kt * 32 + br * 8) * N + nt * 128 + 2 * bp;
            u16 ta[8], tb[8];
#pragma unroll
            for (int j = 0; j < 8; ++j) {
                float2 u = *(const float2*)(s + (size_t)j * N);
                ta[j] = f2bf(u.x); tb[j] = f2bf(u.y);
            }
            *(bf16x8*)&Bs[(2 * bp) * 40 + br * 8]     = *(bf16x8*)&ta[0];
            *(bf16x8*)&Bs[(2 * bp + 1) * 40 + br * 8] = *(bf16x8*)&tb[0];
        }
        __syncthreads();

        bf16x8 afr[4], bfr[4];
#pragma unroll
        for (int m = 0; m < 4; ++m)
            afr[m] = *(const bf16x8*)&As[(wr * 64 + m * 16 + lrow) * 40 + lk];
#pragma unroll
        for (int n = 0; n < 4; ++n)
            bfr[n] = *(const bf16x8*)&Bs[(wc * 64 + n * 16 + lrow) * 40 + lk];
#pragma unroll
        for (int m = 0; m < 4; ++m)
#pragma unroll
            for (int n = 0; n < 4; ++n)
                acc[m][n] = __builtin_amdgcn_mfma_f32_16x16x32_bf16(afr[m], bfr[n], acc[m][n], 0, 0, 0);
        __syncthreads();
    }

    // ---- epilogue.  D mapping: col = lane&15, row = (lane>>4)*4 + reg
#pragma unroll
    for (int m = 0; m < 4; ++m) {
        int rbase = mt * 128 + wr * 64 + m * 16 + (lane >> 4) * 4;
#pragma unroll
        for (int n = 0; n < 4; ++n) {
            int gcol = nt * 128 + wc * 64 + n * 16 + (lane & 15);
            float bv = bias[gcol];
#pragma unroll
            for (int r = 0; r < 4; ++r) {
                int pos = rbase + r;
                if (pos < cnt) {
                    float v = acc[m][n][r] + bv;
                    if constexpr (EPI == 0) {
                        ((u16*)Cg)[(size_t)(off + pos) * N + gcol] = f2bf(gelu_tanh(v));
                    } else {
                        ((float*)Cg)[(size_t)(off + pos) * N + gcol] = v;
                    }
                }
            }
        }
    }
}

// ---------------------------------------------------------------- combine
__global__ __launch_bounds__(256) void k_combine(
    const float* __restrict__ x, const float* __restrict__ P,
    const int* __restrict__ offsets, const int* __restrict__ tok_e,
    const int* __restrict__ tok_pos, const float* __restrict__ tok_w,
    float* __restrict__ out)
{
    int t = blockIdx.x;
    int e0 = tok_e[2 * t], e1 = tok_e[2 * t + 1];
    int r0 = offsets[e0] + tok_pos[2 * t];
    int r1 = offsets[e1] + tok_pos[2 * t + 1];
    int rs = offsets[8] + t;
    float w0 = tok_w[2 * t], w1 = tok_w[2 * t + 1];
    int i = threadIdx.x * 4;

    float4 xv = *(const float4*)(x + (size_t)t * D_DIM + i);
    float4 ps = *(const float4*)(P + (size_t)rs * D_DIM + i);
    float4 p0 = *(const float4*)(P + (size_t)r0 * D_DIM + i);
    float4 p1 = *(const float4*)(P + (size_t)r1 * D_DIM + i);
    float4 o;
    o.x = xv.x + ps.x + w0 * p0.x + w1 * p1.x;
    o.y = xv.y + ps.y + w0 * p0.y + w1 * p1.y;
    o.z = xv.z + ps.z + w0 * p0.z + w1 * p1.z;
    o.w = xv.w + ps.w + w0 * p0.w + w1 * p1.w;
    *(float4*)(out + (size_t)t * D_DIM + i) = o;
}

// ---------------------------------------------------------------- launch
extern "C" void kernel_launch(void* const* d_in, const int* in_sizes, int n_in,
                              void* d_out, int out_size, void* d_ws, size_t ws_size,
                              hipStream_t stream)
{
    const float* x   = (const float*)d_in[0];
    const float* gw  = (const float*)d_in[1];
    const float* gb  = (const float*)d_in[2];
    const float* sw1 = (const float*)d_in[3];
    const float* sb1 = (const float*)d_in[4];
    const float* sw2 = (const float*)d_in[5];
    const float* sb2 = (const float*)d_in[6];
    const float* ew1 = (const float*)d_in[7];
    const float* eb1 = (const float*)d_in[8];
    const float* ew2 = (const float*)d_in[9];
    const float* eb2 = (const float*)d_in[10];

    char* w = (char*)d_ws;
    int* counts  = (int*)w;                       // 16 ints
    int* offsets = (int*)(w + 64);                // 16 ints
    int* tok_e   = (int*)(w + 128);               // 2T ints
    int* tok_pos = tok_e + 2 * T_TOK;             // 2T ints
    float* tok_w = (float*)(tok_pos + 2 * T_TOK); // 2T floats
    int* lists   = (int*)(tok_w + 2 * T_TOK);     // 9T ints
    size_t o = 128 + (size_t)3 * 2 * T_TOK * 4 + (size_t)NE * T_TOK * 4;
    o = (o + 255) & ~(size_t)255;
    u16* H = (u16*)(w + o);                       // 12288 x 4096 bf16
    o += (size_t)3 * T_TOK * I_DIM * 2;
    float* P = (float*)(w + o);                   // 12288 x 1024 f32

    k_init<<<1, 64, 0, stream>>>(counts);
    k_router<<<T_TOK / 4, 256, 0, stream>>>(x, gw, gb, counts, lists, tok_e, tok_pos, tok_w);
    k_prefix<<<1, 64, 0, stream>>>(counts, offsets);

    // GEMM1: h = gelu(Xg @ W1 + b1)  -> H (bf16), N = I
    k_gemm<true, 0><<<dim3(NE * 32, I_DIM / 128), 256, 0, stream>>>(
        (const void*)x, D_DIM, ew1, sw1, eb1, sb1, I_DIM,
        counts, offsets, lists, (void*)H, D_DIM, I_DIM);

    // GEMM2: P = H @ W2 + b2  (unscaled, f32), N = D
    k_gemm<false, 1><<<dim3(NE * 32, D_DIM / 128), 256, 0, stream>>>(
        (const void*)H, I_DIM, ew2, sw2, eb2, sb2, D_DIM,
        counts, offsets, lists, (void*)P, I_DIM, D_DIM);

    // combine: out = x + P_shared + w0*P_e0 + w1*P_e1
    k_combine<<<T_TOK, 256, 0, stream>>>(x, P, offsets, tok_e, tok_pos, tok_w, (float*)d_out);
}

// Round 2
// 1150.563 us; speedup vs baseline: 1.3479x; 1.3479x over previous
//
#include <hip/hip_runtime.h>
#include <hip/hip_bf16.h>
#include <stdint.h>

typedef short bf16x8 __attribute__((ext_vector_type(8)));
typedef float f32x4  __attribute__((ext_vector_type(4)));
typedef unsigned short u16;

#define T_TOK 4096
#define D_DIM 1024
#define I_DIM 4096
#define NE    9      // 8 routed experts + 1 shared "expert"
#define BK    32

__device__ __forceinline__ u16 f2bf(float f) {
    union { float f; uint32_t u; } v; v.f = f;
    uint32_t u = v.u;
    u += 0x7FFFu + ((u >> 16) & 1u);   // round-to-nearest-even
    return (u16)(u >> 16);
}

__device__ __forceinline__ float gelu_tanh(float v) {
    float c = 0.7978845608028654f * (v + 0.044715f * v * v * v);
    return 0.5f * v * (1.0f + tanhf(c));
}

// async global->LDS, 16B per lane. LDS dest: wave-uniform base + lane*16.
__device__ __forceinline__ void gl16(const void* g, void* l) {
    __builtin_amdgcn_global_load_lds(
        (const __attribute__((address_space(1))) void*)g,
        (__attribute__((address_space(3))) void*)l, 16, 0, 0);
}

// ---------------------------------------------------------------- init
__global__ void k_init(int* counts) {
    int i = threadIdx.x;
    if (i < 16) counts[i] = (i == 8) ? T_TOK : 0;
}

// ---------------------------------------------------------------- router
__global__ __launch_bounds__(256) void k_router(
    const float* __restrict__ x, const float* __restrict__ gw,
    const float* __restrict__ gb,
    int* counts, int* lists, int* tok_e, int* tok_pos, float* tok_w)
{
    int wave = threadIdx.x >> 6, lane = threadIdx.x & 63;
    int t = blockIdx.x * 4 + wave;
    const float* xr = x + (size_t)t * D_DIM;

    float a[8];
#pragma unroll
    for (int e = 0; e < 8; ++e) a[e] = 0.f;
#pragma unroll
    for (int j = 0; j < D_DIM / 64; ++j) {
        int d = lane + 64 * j;
        float xv = xr[d];
        const float4* g = (const float4*)(gw + (size_t)d * 8);
        float4 g0 = g[0], g1 = g[1];
        a[0] += xv * g0.x; a[1] += xv * g0.y; a[2] += xv * g0.z; a[3] += xv * g0.w;
        a[4] += xv * g1.x; a[5] += xv * g1.y; a[6] += xv * g1.z; a[7] += xv * g1.w;
    }
#pragma unroll
    for (int off = 32; off >= 1; off >>= 1)
#pragma unroll
        for (int e = 0; e < 8; ++e) a[e] += __shfl_xor(a[e], off);

    float l[8];
#pragma unroll
    for (int e = 0; e < 8; ++e) l[e] = a[e] + gb[e];
    float mx = l[0];
#pragma unroll
    for (int e = 1; e < 8; ++e) mx = fmaxf(mx, l[e]);
    float p[8], Z = 0.f;
#pragma unroll
    for (int e = 0; e < 8; ++e) { p[e] = expf(l[e] - mx); Z += p[e]; }
#pragma unroll
    for (int e = 0; e < 8; ++e) p[e] /= Z;

    int e0 = 0; float v0 = p[0];
#pragma unroll
    for (int e = 1; e < 8; ++e) if (p[e] > v0) { v0 = p[e]; e0 = e; }
    int e1 = -1; float v1 = -1.f;
#pragma unroll
    for (int e = 0; e < 8; ++e) if (e != e0 && p[e] > v1) { v1 = p[e]; e1 = e; }
    float denom = v0 + v1 + 1e-9f;
    float w0 = v0 / denom, w1 = v1 / denom;

    if (lane == 0) {
        int p0 = atomicAdd(&counts[e0], 1);
        int p1 = atomicAdd(&counts[e1], 1);
        lists[e0 * T_TOK + p0] = t;
        lists[e1 * T_TOK + p1] = t;
        tok_e[2 * t] = e0;  tok_e[2 * t + 1] = e1;
        tok_pos[2 * t] = p0; tok_pos[2 * t + 1] = p1;
        tok_w[2 * t] = w0;  tok_w[2 * t + 1] = w1;
    }
}

// ---------------------------------------------------------------- prefix
__global__ void k_prefix(const int* counts, int* offsets) {
    if (threadIdx.x == 0) {
        int o = 0;
        for (int e = 0; e < NE; ++e) { offsets[e] = o; o += counts[e]; }
        offsets[NE] = o;
    }
}

// ---------------------------------------------------------------- cast x -> bf16 dense
__global__ __launch_bounds__(256) void k_castx(const float* __restrict__ x,
                                               u16* __restrict__ xb)
{
    int i = (blockIdx.x * 256 + threadIdx.x) * 8;
    float4 a = *(const float4*)(x + i), b = *(const float4*)(x + i + 4);
    u16 t[8] = { f2bf(a.x), f2bf(a.y), f2bf(a.z), f2bf(a.w),
                 f2bf(b.x), f2bf(b.y), f2bf(b.z), f2bf(b.w) };
    *(bf16x8*)&xb[i] = *(bf16x8*)t;
}

// ---------------------------------------------------------------- transpose-cast weights
// src f32 [z][K][N] tilewise -> dst bf16 [z][N][K]
__global__ __launch_bounds__(256) void k_transcast(
    const float* __restrict__ src, u16* __restrict__ dst, int K, int N)
{
    src += (size_t)blockIdx.z * K * N;
    dst += (size_t)blockIdx.z * N * K;
    __shared__ float ls[64][33];
    int t = threadIdx.x;
    int k0 = blockIdx.y * 64, n0 = blockIdx.x * 32;
    {
        int kr = t >> 2, ng = (t & 3) * 8;
        const float* s = src + (size_t)(k0 + kr) * N + n0 + ng;
        float4 v0 = *(const float4*)s, v1 = *(const float4*)(s + 4);
        ls[kr][ng + 0] = v0.x; ls[kr][ng + 1] = v0.y; ls[kr][ng + 2] = v0.z; ls[kr][ng + 3] = v0.w;
        ls[kr][ng + 4] = v1.x; ls[kr][ng + 5] = v1.y; ls[kr][ng + 6] = v1.z; ls[kr][ng + 7] = v1.w;
    }
    __syncthreads();
    int n = t >> 3, kg = (t & 7) * 8;
    u16 o[8];
#pragma unroll
    for (int j = 0; j < 8; ++j) o[j] = f2bf(ls[kg + j][n]);
    *(bf16x8*)&dst[(size_t)(n0 + n) * K + k0 + kg] = *(bf16x8*)o;
}

// ---------------------------------------------------------------- grouped GEMM (m97 structure)
// 128x128 tile, BK=32, 4 waves 2x2, mfma_f32_16x16x32_bf16, global_load_lds dwordx4.
// A: bf16 rows k-minor. Bt: bf16 [NE][N][K].
// GEMM==1: A=xb gathered via lists, epilogue gelu->bf16 H at row off+pos.
// GEMM==2: A=H contiguous at off, epilogue +bias -> f32 P.
template <int GEMM>
__global__ __launch_bounds__(256)
void k_gemm(const u16* __restrict__ A, const u16* __restrict__ Bt,
            const float* __restrict__ be, const float* __restrict__ bsh,
            const int* __restrict__ counts, const int* __restrict__ offsets,
            const int* __restrict__ lists, void* __restrict__ Cg,
            const int K, const int N)
{
    const int e = blockIdx.z, mt = blockIdx.x, nt = blockIdx.y;
    const int cnt = counts[e];
    if (mt * 128 >= cnt) return;
    const int off = offsets[e];

    __shared__ __align__(16) u16 As[128 * BK];
    __shared__ __align__(16) u16 Bs[128 * BK];

    const int tid = threadIdx.x, w = tid >> 6, l = tid & 63;
    const int r0 = w * 32 + (l >> 2);         // row covered by this lane, q=0
    const u16* Be = Bt + (size_t)e * N * K;

    const u16* aptr[2];
    const u16* bptr[2];
#pragma unroll
    for (int q = 0; q < 2; ++q) {
        int row = mt * 128 + r0 + q * 16;
        int srow;
        if constexpr (GEMM == 1) {
            if (e == 8) srow = row;  // shared expert: token id == row
            else {
                int rc = row < cnt ? row : cnt - 1;
                srow = lists[e * T_TOK + rc];
            }
        } else {
            srow = off + row;        // contiguous H rows (overhang reads discarded)
        }
        aptr[q] = A + (size_t)srow * K + (l & 3) * 8;
        bptr[q] = Be + (size_t)(nt * 128 + r0 + q * 16) * K + (l & 3) * 8;
    }
    u16* asl[2] = { As + w * 1024, As + w * 1024 + 512 };
    u16* bsl[2] = { Bs + w * 1024, Bs + w * 1024 + 512 };

    const int lrow = l & 15, lk = (l >> 4) * 8;
    const int wr = w >> 1, wc = w & 1;

    f32x4 zero = {0.f, 0.f, 0.f, 0.f};
    f32x4 acc[4][4];
#pragma unroll
    for (int m = 0; m < 4; ++m)
#pragma unroll
        for (int n = 0; n < 4; ++n) acc[m][n] = zero;

    const int nk = K / BK;
    for (int kt = 0; kt < nk; ++kt) {
        const int ko = kt * BK;
#pragma unroll
        for (int q = 0; q < 2; ++q) {
            gl16(aptr[q] + ko, asl[q]);
            gl16(bptr[q] + ko, bsl[q]);
        }
        __syncthreads();   // compiler drains vmcnt before barrier

        bf16x8 afr[4], bfr[4];
#pragma unroll
        for (int m = 0; m < 4; ++m)
            afr[m] = *(const bf16x8*)&As[(wr * 64 + m * 16 + lrow) * BK + lk];
#pragma unroll
        for (int n = 0; n < 4; ++n)
            bfr[n] = *(const bf16x8*)&Bs[(wc * 64 + n * 16 + lrow) * BK + lk];
#pragma unroll
        for (int m = 0; m < 4; ++m)
#pragma unroll
            for (int n = 0; n < 4; ++n)
                acc[m][n] = __builtin_amdgcn_mfma_f32_16x16x32_bf16(afr[m], bfr[n], acc[m][n], 0, 0, 0);
        __syncthreads();
    }

    const float* bias = (e == 8) ? bsh : (be + (size_t)e * N);
#pragma unroll
    for (int m = 0; m < 4; ++m) {
        int pbase = mt * 128 + wr * 64 + m * 16 + (l >> 4) * 4;
#pragma unroll
        for (int n = 0; n < 4; ++n) {
            int gcol = nt * 128 + wc * 64 + n * 16 + (l & 15);
            float bv = bias[gcol];
#pragma unroll
            for (int r = 0; r < 4; ++r) {
                int pos = pbase + r;
                if (pos < cnt) {
                    float v = acc[m][n][r] + bv;
                    if constexpr (GEMM == 1)
                        ((u16*)Cg)[(size_t)(off + pos) * N + gcol] = f2bf(gelu_tanh(v));
                    else
                        ((float*)Cg)[(size_t)(off + pos) * N + gcol] = v;
                }
            }
        }
    }
}

// ---------------------------------------------------------------- combine
__global__ __launch_bounds__(256) void k_combine(
    const float* __restrict__ x, const float* __restrict__ P,
    const int* __restrict__ offsets, const int* __restrict__ tok_e,
    const int* __restrict__ tok_pos, const float* __restrict__ tok_w,
    float* __restrict__ out)
{
    int t = blockIdx.x;
    int e0 = tok_e[2 * t], e1 = tok_e[2 * t + 1];
    int r0 = offsets[e0] + tok_pos[2 * t];
    int r1 = offsets[e1] + tok_pos[2 * t + 1];
    int rs = offsets[8] + t;
    float w0 = tok_w[2 * t], w1 = tok_w[2 * t + 1];
    int i = threadIdx.x * 4;

    float4 xv = *(const float4*)(x + (size_t)t * D_DIM + i);
    float4 ps = *(const float4*)(P + (size_t)rs * D_DIM + i);
    float4 p0 = *(const float4*)(P + (size_t)r0 * D_DIM + i);
    float4 p1 = *(const float4*)(P + (size_t)r1 * D_DIM + i);
    float4 o;
    o.x = xv.x + ps.x + w0 * p0.x + w1 * p1.x;
    o.y = xv.y + ps.y + w0 * p0.y + w1 * p1.y;
    o.z = xv.z + ps.z + w0 * p0.z + w1 * p1.z;
    o.w = xv.w + ps.w + w0 * p0.w + w1 * p1.w;
    *(float4*)(out + (size_t)t * D_DIM + i) = o;
}

// ---------------------------------------------------------------- launch
extern "C" void kernel_launch(void* const* d_in, const int* in_sizes, int n_in,
                              void* d_out, int out_size, void* d_ws, size_t ws_size,
                              hipStream_t stream)
{
    const float* x   = (const float*)d_in[0];
    const float* gw  = (const float*)d_in[1];
    const float* gb  = (const float*)d_in[2];
    const float* sw1 = (const float*)d_in[3];
    const float* sb1 = (const float*)d_in[4];
    const float* sw2 = (const float*)d_in[5];
    const float* sb2 = (const float*)d_in[6];
    const float* ew1 = (const float*)d_in[7];
    const float* eb1 = (const float*)d_in[8];
    const float* ew2 = (const float*)d_in[9];
    const float* eb2 = (const float*)d_in[10];

    char* w = (char*)d_ws;
    int* counts  = (int*)w;                       // 16 ints
    int* offsets = (int*)(w + 64);                // 16 ints
    int* tok_e   = (int*)(w + 128);               // 2T ints
    int* tok_pos = tok_e + 2 * T_TOK;             // 2T ints
    float* tok_w = (float*)(tok_pos + 2 * T_TOK); // 2T floats
    int* lists   = (int*)(tok_w + 2 * T_TOK);     // 8T ints (routed only)

    size_t o = (size_t)1 << 20;                   // 1MB: small buffers above
    u16* xb  = (u16*)(w + o);                     // 4096 x 1024 bf16 (8MB)
    o += (size_t)T_TOK * D_DIM * 2;
    u16* H   = (u16*)(w + o);                     // 12288 x 4096 bf16 (96MB)
    o += (size_t)3 * T_TOK * I_DIM * 2;
    u16* Wt  = (u16*)(w + o);                     // 9 x 4096 x 1024 bf16 (72MB), W1t then W2t
    o += (size_t)NE * I_DIM * D_DIM * 2;
    float* P = (float*)(w + o);                   // 12288 x 1024 f32 (48MB)

    k_init<<<1, 64, 0, stream>>>(counts);

    // W1^T: [K=1024][N=4096] -> bf16 [4096][1024]
    k_transcast<<<dim3(I_DIM / 32, D_DIM / 64, 8), 256, 0, stream>>>(ew1, Wt, D_DIM, I_DIM);
    k_transcast<<<dim3(I_DIM / 32, D_DIM / 64, 1), 256, 0, stream>>>(
        sw1, Wt + (size_t)8 * I_DIM * D_DIM, D_DIM, I_DIM);
    k_castx<<<T_TOK * D_DIM / (256 * 8), 256, 0, stream>>>(x, xb);

    k_router<<<T_TOK / 4, 256, 0, stream>>>(x, gw, gb, counts, lists, tok_e, tok_pos, tok_w);
    k_prefix<<<1, 64, 0, stream>>>(counts, offsets);

    // GEMM1: H = gelu(Xg @ W1 + b1), N = I
    k_gemm<1><<<dim3(32, I_DIM / 128, NE), 256, 0, stream>>>(
        xb, Wt, eb1, sb1, counts, offsets, lists, (void*)H, D_DIM, I_DIM);

    // W2^T: [K=4096][N=1024] -> bf16 [1024][4096]  (aliases W1t region; stream-ordered)
    k_transcast<<<dim3(D_DIM / 32, I_DIM / 64, 8), 256, 0, stream>>>(ew2, Wt, I_DIM, D_DIM);
    k_transcast<<<dim3(D_DIM / 32, I_DIM / 64, 1), 256, 0, stream>>>(
        sw2, Wt + (size_t)8 * I_DIM * D_DIM, I_DIM, D_DIM);

    // GEMM2: P = H @ W2 + b2, N = D
    k_gemm<2><<<dim3(32, D_DIM / 128, NE), 256, 0, stream>>>(
        H, Wt, eb2, sb2, counts, offsets, lists, (void*)P, I_DIM, D_DIM);

    k_combine<<<T_TOK, 256, 0, stream>>>(x, P, offsets, tok_e, tok_pos, tok_w, (float*)d_out);
}

// Round 3
// 1115.499 us; speedup vs baseline: 1.3902x; 1.0314x over previous
//
#include <hip/hip_runtime.h>
#include <hip/hip_bf16.h>
#include <stdint.h>

typedef short bf16x8 __attribute__((ext_vector_type(8)));
typedef float f32x4  __attribute__((ext_vector_type(4)));
typedef unsigned short u16;

#define T_TOK 4096
#define D_DIM 1024
#define I_DIM 4096
#define NE    9      // 8 routed experts + 1 shared "expert"
#define BK    32

__device__ __forceinline__ u16 f2bf(float f) {
    union { float f; uint32_t u; } v; v.f = f;
    uint32_t u = v.u;
    u += 0x7FFFu + ((u >> 16) & 1u);   // round-to-nearest-even
    return (u16)(u >> 16);
}

// gelu(tanh approx) via sigmoid identity: 0.5v(1+tanh(c)) = v/(1+e^{-2c})
__device__ __forceinline__ float gelu_fast(float v) {
    float c2 = 1.5957691216057308f * (v + 0.044715f * v * v * v);
    return v / (1.0f + __expf(-c2));
}

// async global->LDS, 16B per lane. LDS dest: wave-uniform base + lane*16.
__device__ __forceinline__ void gl16(const void* g, void* l) {
    __builtin_amdgcn_global_load_lds(
        (const __attribute__((address_space(1))) void*)g,
        (__attribute__((address_space(3))) void*)l, 16, 0, 0);
}

// ---------------------------------------------------------------- init
__global__ void k_init(int* counts) {
    int i = threadIdx.x;
    if (i < 16) counts[i] = (i == 8) ? T_TOK : 0;
}

// ---------------------------------------------------------------- router
__global__ __launch_bounds__(256) void k_router(
    const float* __restrict__ x, const float* __restrict__ gw,
    const float* __restrict__ gb,
    int* counts, int* lists, int* tok_e, int* tok_pos, float* tok_w)
{
    int wave = threadIdx.x >> 6, lane = threadIdx.x & 63;
    int t = blockIdx.x * 4 + wave;
    const float* xr = x + (size_t)t * D_DIM;

    float a[8];
#pragma unroll
    for (int e = 0; e < 8; ++e) a[e] = 0.f;
#pragma unroll
    for (int j = 0; j < D_DIM / 64; ++j) {
        int d = lane + 64 * j;
        float xv = xr[d];
        const float4* g = (const float4*)(gw + (size_t)d * 8);
        float4 g0 = g[0], g1 = g[1];
        a[0] += xv * g0.x; a[1] += xv * g0.y; a[2] += xv * g0.z; a[3] += xv * g0.w;
        a[4] += xv * g1.x; a[5] += xv * g1.y; a[6] += xv * g1.z; a[7] += xv * g1.w;
    }
#pragma unroll
    for (int off = 32; off >= 1; off >>= 1)
#pragma unroll
        for (int e = 0; e < 8; ++e) a[e] += __shfl_xor(a[e], off);

    float l[8];
#pragma unroll
    for (int e = 0; e < 8; ++e) l[e] = a[e] + gb[e];
    float mx = l[0];
#pragma unroll
    for (int e = 1; e < 8; ++e) mx = fmaxf(mx, l[e]);
    float p[8], Z = 0.f;
#pragma unroll
    for (int e = 0; e < 8; ++e) { p[e] = expf(l[e] - mx); Z += p[e]; }
#pragma unroll
    for (int e = 0; e < 8; ++e) p[e] /= Z;

    int e0 = 0; float v0 = p[0];
#pragma unroll
    for (int e = 1; e < 8; ++e) if (p[e] > v0) { v0 = p[e]; e0 = e; }
    int e1 = -1; float v1 = -1.f;
#pragma unroll
    for (int e = 0; e < 8; ++e) if (e != e0 && p[e] > v1) { v1 = p[e]; e1 = e; }
    float denom = v0 + v1 + 1e-9f;
    float w0 = v0 / denom, w1 = v1 / denom;

    if (lane == 0) {
        int p0 = atomicAdd(&counts[e0], 1);
        int p1 = atomicAdd(&counts[e1], 1);
        lists[e0 * T_TOK + p0] = t;
        lists[e1 * T_TOK + p1] = t;
        tok_e[2 * t] = e0;  tok_e[2 * t + 1] = e1;
        tok_pos[2 * t] = p0; tok_pos[2 * t + 1] = p1;
        tok_w[2 * t] = w0;  tok_w[2 * t + 1] = w1;
    }
}

// ---------------------------------------------------------------- prefix
__global__ void k_prefix(const int* counts, int* offsets) {
    if (threadIdx.x == 0) {
        int o = 0;
        for (int e = 0; e < NE; ++e) { offsets[e] = o; o += counts[e]; }
        offsets[NE] = o;
    }
}

// ---------------------------------------------------------------- cast x -> bf16 dense
__global__ __launch_bounds__(256) void k_castx(const float* __restrict__ x,
                                               u16* __restrict__ xb)
{
    int i = (blockIdx.x * 256 + threadIdx.x) * 8;
    float4 a = *(const float4*)(x + i), b = *(const float4*)(x + i + 4);
    u16 t[8] = { f2bf(a.x), f2bf(a.y), f2bf(a.z), f2bf(a.w),
                 f2bf(b.x), f2bf(b.y), f2bf(b.z), f2bf(b.w) };
    *(bf16x8*)&xb[i] = *(bf16x8*)t;
}

// ---------------------------------------------------------------- transpose-cast weights
// src f32 [z][K][N] tilewise -> dst bf16 [z][N][K]
__global__ __launch_bounds__(256) void k_transcast(
    const float* __restrict__ src, u16* __restrict__ dst, int K, int N)
{
    src += (size_t)blockIdx.z * K * N;
    dst += (size_t)blockIdx.z * N * K;
    __shared__ float ls[64][33];
    int t = threadIdx.x;
    int k0 = blockIdx.y * 64, n0 = blockIdx.x * 32;
    {
        int kr = t >> 2, ng = (t & 3) * 8;
        const float* s = src + (size_t)(k0 + kr) * N + n0 + ng;
        float4 v0 = *(const float4*)s, v1 = *(const float4*)(s + 4);
        ls[kr][ng + 0] = v0.x; ls[kr][ng + 1] = v0.y; ls[kr][ng + 2] = v0.z; ls[kr][ng + 3] = v0.w;
        ls[kr][ng + 4] = v1.x; ls[kr][ng + 5] = v1.y; ls[kr][ng + 6] = v1.z; ls[kr][ng + 7] = v1.w;
    }
    __syncthreads();
    int n = t >> 3, kg = (t & 7) * 8;
    u16 o[8];
#pragma unroll
    for (int j = 0; j < 8; ++j) o[j] = f2bf(ls[kg + j][n]);
    *(bf16x8*)&dst[(size_t)(n0 + n) * K + k0 + kg] = *(bf16x8*)o;
}

// ---------------------------------------------------------------- grouped GEMM
// 128x128 tile, BK=32, 4 waves 2x2, mfma_f32_16x16x32_bf16.
// 2-phase double-buffered LDS pipeline (T3 minimum): stage tile t+1 before
// computing tile t; one vmcnt-drain+barrier per tile.
// XCD-chunked work remap (T1, bijective: total%8==0).
// GEMM==1: A=xb gathered via lists (K=1024,N=4096), epi gelu->bf16 H, mt-fastest.
// GEMM==2: A=H contiguous (K=4096,N=1024), epi +bias->f32 P, nt-fastest.
template <int GEMM>
__global__ __launch_bounds__(256)
void k_gemm(const u16* __restrict__ A, const u16* __restrict__ Bt,
            const float* __restrict__ be, const float* __restrict__ bsh,
            const int* __restrict__ counts, const int* __restrict__ offsets,
            const int* __restrict__ lists, void* __restrict__ Cg)
{
    constexpr int K  = (GEMM == 1) ? D_DIM : I_DIM;
    constexpr int N  = (GEMM == 1) ? I_DIM : D_DIM;
    constexpr int NT = N / 128;              // n-tiles
    constexpr int TOTW = 32 * NT * NE;       // 9216 / 2304, both %8==0

    // ---- XCD-chunked bijective remap: XCD k owns a contiguous work range
    int lin = blockIdx.x + 32 * (blockIdx.y + NT * blockIdx.z);
    int work = (lin & 7) * (TOTW / 8) + (lin >> 3);
    int mt, nt, e;
    if constexpr (GEMM == 1) {               // mt-fastest: concurrent blocks share B
        mt = work & 31; int r = work >> 5; nt = r & 31; e = r >> 5;
    } else {                                 // nt-fastest: concurrent blocks share A
        nt = work & 7;  int r = work >> 3; mt = r & 31; e = r >> 5;
    }

    const int cnt = counts[e];
    if (mt * 128 >= cnt) return;
    const int off = offsets[e];

    __shared__ __align__(16) u16 As0[128 * BK];
    __shared__ __align__(16) u16 Bs0[128 * BK];
    __shared__ __align__(16) u16 As1[128 * BK];
    __shared__ __align__(16) u16 Bs1[128 * BK];

    const int tid = threadIdx.x, w = tid >> 6, l = tid & 63;
    const int wu = __builtin_amdgcn_readfirstlane(w);   // uniform wave id for LDS base
    const int r0 = w * 32 + (l >> 2);                   // row this lane stages, q=0
    const u16* Be = Bt + (size_t)e * N * K;

    const u16* aptr[2];
    const u16* bptr[2];
#pragma unroll
    for (int q = 0; q < 2; ++q) {
        int row = mt * 128 + r0 + q * 16;
        int srow;
        if constexpr (GEMM == 1) {
            if (e == 8) srow = row;          // shared expert: token id == row
            else {
                int rc = row < cnt ? row : cnt - 1;
                srow = lists[e * T_TOK + rc];
            }
        } else {
            srow = off + row;                // contiguous H rows
        }
        aptr[q] = A + (size_t)srow * K + (l & 3) * 8;
        bptr[q] = Be + (size_t)(nt * 128 + r0 + q * 16) * K + (l & 3) * 8;
    }

    const int lrow = l & 15, lk = (l >> 4) * 8;
    const int wr = w >> 1, wc = w & 1;

    f32x4 zero = {0.f, 0.f, 0.f, 0.f};
    f32x4 acc[4][4];
#pragma unroll
    for (int m = 0; m < 4; ++m)
#pragma unroll
        for (int n = 0; n < 4; ++n) acc[m][n] = zero;

    auto stage = [&](u16* As_, u16* Bs_, int ko) {
#pragma unroll
        for (int q = 0; q < 2; ++q) {
            gl16(aptr[q] + ko, As_ + wu * 1024 + q * 512);
            gl16(bptr[q] + ko, Bs_ + wu * 1024 + q * 512);
        }
    };
    auto compute = [&](const u16* As_, const u16* Bs_) {
        bf16x8 afr[4], bfr[4];
#pragma unroll
        for (int m = 0; m < 4; ++m)
            afr[m] = *(const bf16x8*)&As_[(wr * 64 + m * 16 + lrow) * BK + lk];
#pragma unroll
        for (int n = 0; n < 4; ++n)
            bfr[n] = *(const bf16x8*)&Bs_[(wc * 64 + n * 16 + lrow) * BK + lk];
#pragma unroll
        for (int m = 0; m < 4; ++m)
#pragma unroll
            for (int n = 0; n < 4; ++n)
                acc[m][n] = __builtin_amdgcn_mfma_f32_16x16x32_bf16(afr[m], bfr[n], acc[m][n], 0, 0, 0);
    };

    constexpr int nk = K / BK;               // 32 or 128, even
    stage(As0, Bs0, 0);
    __syncthreads();
    for (int kt = 0; kt + 2 < nk; kt += 2) {
        stage(As1, Bs1, (kt + 1) * BK);      // prefetch issued BEFORE compute
        compute(As0, Bs0);
        __syncthreads();                     // drains the As1/Bs1 stage
        stage(As0, Bs0, (kt + 2) * BK);
        compute(As1, Bs1);
        __syncthreads();
    }
    stage(As1, Bs1, (nk - 1) * BK);
    compute(As0, Bs0);
    __syncthreads();
    compute(As1, Bs1);

    // ---- epilogue.  D mapping: col = lane&15, row = (lane>>4)*4 + reg
    const float* bias = (e == 8) ? bsh : (be + (size_t)e * N);
#pragma unroll
    for (int m = 0; m < 4; ++m) {
        int pbase = mt * 128 + wr * 64 + m * 16 + (l >> 4) * 4;
#pragma unroll
        for (int n = 0; n < 4; ++n) {
            int gcol = nt * 128 + wc * 64 + n * 16 + (l & 15);
            float bv = bias[gcol];
#pragma unroll
            for (int r = 0; r < 4; ++r) {
                int pos = pbase + r;
                if (pos < cnt) {
                    float v = acc[m][n][r] + bv;
                    if constexpr (GEMM == 1)
                        ((u16*)Cg)[(size_t)(off + pos) * N + gcol] = f2bf(gelu_fast(v));
                    else
                        ((float*)Cg)[(size_t)(off + pos) * N + gcol] = v;
                }
            }
        }
    }
}

// ---------------------------------------------------------------- combine
__global__ __launch_bounds__(256) void k_combine(
    const float* __restrict__ x, const float* __restrict__ P,
    const int* __restrict__ offsets, const int* __restrict__ tok_e,
    const int* __restrict__ tok_pos, const float* __restrict__ tok_w,
    float* __restrict__ out)
{
    int t = blockIdx.x;
    int e0 = tok_e[2 * t], e1 = tok_e[2 * t + 1];
    int r0 = offsets[e0] + tok_pos[2 * t];
    int r1 = offsets[e1] + tok_pos[2 * t + 1];
    int rs = offsets[8] + t;
    float w0 = tok_w[2 * t], w1 = tok_w[2 * t + 1];
    int i = threadIdx.x * 4;

    float4 xv = *(const float4*)(x + (size_t)t * D_DIM + i);
    float4 ps = *(const float4*)(P + (size_t)rs * D_DIM + i);
    float4 p0 = *(const float4*)(P + (size_t)r0 * D_DIM + i);
    float4 p1 = *(const float4*)(P + (size_t)r1 * D_DIM + i);
    float4 o;
    o.x = xv.x + ps.x + w0 * p0.x + w1 * p1.x;
    o.y = xv.y + ps.y + w0 * p0.y + w1 * p1.y;
    o.z = xv.z + ps.z + w0 * p0.z + w1 * p1.z;
    o.w = xv.w + ps.w + w0 * p0.w + w1 * p1.w;
    *(float4*)(out + (size_t)t * D_DIM + i) = o;
}

// ---------------------------------------------------------------- launch
extern "C" void kernel_launch(void* const* d_in, const int* in_sizes, int n_in,
                              void* d_out, int out_size, void* d_ws, size_t ws_size,
                              hipStream_t stream)
{
    const float* x   = (const float*)d_in[0];
    const float* gw  = (const float*)d_in[1];
    const float* gb  = (const float*)d_in[2];
    const float* sw1 = (const float*)d_in[3];
    const float* sb1 = (const float*)d_in[4];
    const float* sw2 = (const float*)d_in[5];
    const float* sb2 = (const float*)d_in[6];
    const float* ew1 = (const float*)d_in[7];
    const float* eb1 = (const float*)d_in[8];
    const float* ew2 = (const float*)d_in[9];
    const float* eb2 = (const float*)d_in[10];

    char* w = (char*)d_ws;
    int* counts  = (int*)w;                       // 16 ints
    int* offsets = (int*)(w + 64);                // 16 ints
    int* tok_e   = (int*)(w + 128);               // 2T ints
    int* tok_pos = tok_e + 2 * T_TOK;             // 2T ints
    float* tok_w = (float*)(tok_pos + 2 * T_TOK); // 2T floats
    int* lists   = (int*)(tok_w + 2 * T_TOK);     // 8T ints (routed only)

    size_t o = (size_t)1 << 20;                   // 1MB: small buffers above
    u16* xb  = (u16*)(w + o);                     // 4096 x 1024 bf16 (8MB)
    o += (size_t)T_TOK * D_DIM * 2;
    u16* H   = (u16*)(w + o);                     // 12288 x 4096 bf16 (96MB)
    o += (size_t)3 * T_TOK * I_DIM * 2;
    u16* Wt  = (u16*)(w + o);                     // 9 x 4096 x 1024 bf16 (72MB), W1t then W2t
    o += (size_t)NE * I_DIM * D_DIM * 2;
    float* P = (float*)(w + o);                   // 12288 x 1024 f32 (48MB)

    k_init<<<1, 64, 0, stream>>>(counts);

    // W1^T: [K=1024][N=4096] -> bf16 [4096][1024]
    k_transcast<<<dim3(I_DIM / 32, D_DIM / 64, 8), 256, 0, stream>>>(ew1, Wt, D_DIM, I_DIM);
    k_transcast<<<dim3(I_DIM / 32, D_DIM / 64, 1), 256, 0, stream>>>(
        sw1, Wt + (size_t)8 * I_DIM * D_DIM, D_DIM, I_DIM);
    k_castx<<<T_TOK * D_DIM / (256 * 8), 256, 0, stream>>>(x, xb);

    k_router<<<T_TOK / 4, 256, 0, stream>>>(x, gw, gb, counts, lists, tok_e, tok_pos, tok_w);
    k_prefix<<<1, 64, 0, stream>>>(counts, offsets);

    // GEMM1: H = gelu(Xg @ W1 + b1), N = I
    k_gemm<1><<<dim3(32, I_DIM / 128, NE), 256, 0, stream>>>(
        xb, Wt, eb1, sb1, counts, offsets, lists, (void*)H);

    // W2^T: [K=4096][N=1024] -> bf16 [1024][4096]  (aliases W1t region; stream-ordered)
    k_transcast<<<dim3(D_DIM / 32, I_DIM / 64, 8), 256, 0, stream>>>(ew2, Wt, I_DIM, D_DIM);
    k_transcast<<<dim3(D_DIM / 32, I_DIM / 64, 1), 256, 0, stream>>>(
        sw2, Wt + (size_t)8 * I_DIM * D_DIM, I_DIM, D_DIM);

    // GEMM2: P = H @ W2 + b2, N = D
    k_gemm<2><<<dim3(32, D_DIM / 128, NE), 256, 0, stream>>>(
        H, Wt, eb2, sb2, counts, offsets, lists, (void*)P);

    k_combine<<<T_TOK, 256, 0, stream>>>(x, P, offsets, tok_e, tok_pos, tok_w, (float*)d_out);
}

// Round 4
// 1035.908 us; speedup vs baseline: 1.4971x; 1.0768x over previous
//
#include <hip/hip_runtime.h>
#include <hip/hip_bf16.h>
#include <stdint.h>

typedef short bf16x8 __attribute__((ext_vector_type(8)));
typedef float f32x4  __attribute__((ext_vector_type(4)));
typedef unsigned short u16;

#define T_TOK 4096
#define D_DIM 1024
#define I_DIM 4096
#define NE    9      // 8 routed experts + 1 shared "expert"
#define BK    32

__device__ __forceinline__ u16 f2bf(float f) {
    union { float f; uint32_t u; } v; v.f = f;
    uint32_t u = v.u;
    u += 0x7FFFu + ((u >> 16) & 1u);   // round-to-nearest-even
    return (u16)(u >> 16);
}

// gelu(tanh approx) via sigmoid identity: 0.5v(1+tanh(c)) = v/(1+e^{-2c})
__device__ __forceinline__ float gelu_fast(float v) {
    float c2 = 1.5957691216057308f * (v + 0.044715f * v * v * v);
    return v / (1.0f + __expf(-c2));
}

// async global->LDS, 16B per lane. LDS dest: wave-uniform base + lane*16.
__device__ __forceinline__ void gl16(const void* g, void* l) {
    __builtin_amdgcn_global_load_lds(
        (const __attribute__((address_space(1))) void*)g,
        (__attribute__((address_space(3))) void*)l, 16, 0, 0);
}

// ---------------------------------------------------------------- init
__global__ void k_init(int* counts) {
    int i = threadIdx.x;
    if (i < 16) counts[i] = (i == 8) ? T_TOK : 0;
}

// ---------------------------------------------------------------- router
__global__ __launch_bounds__(256) void k_router(
    const float* __restrict__ x, const float* __restrict__ gw,
    const float* __restrict__ gb,
    int* counts, int* lists, int* tok_e, int* tok_pos, float* tok_w)
{
    int wave = threadIdx.x >> 6, lane = threadIdx.x & 63;
    int t = blockIdx.x * 4 + wave;
    const float* xr = x + (size_t)t * D_DIM;

    float a[8];
#pragma unroll
    for (int e = 0; e < 8; ++e) a[e] = 0.f;
#pragma unroll
    for (int j = 0; j < D_DIM / 64; ++j) {
        int d = lane + 64 * j;
        float xv = xr[d];
        const float4* g = (const float4*)(gw + (size_t)d * 8);
        float4 g0 = g[0], g1 = g[1];
        a[0] += xv * g0.x; a[1] += xv * g0.y; a[2] += xv * g0.z; a[3] += xv * g0.w;
        a[4] += xv * g1.x; a[5] += xv * g1.y; a[6] += xv * g1.z; a[7] += xv * g1.w;
    }
#pragma unroll
    for (int off = 32; off >= 1; off >>= 1)
#pragma unroll
        for (int e = 0; e < 8; ++e) a[e] += __shfl_xor(a[e], off);

    float l[8];
#pragma unroll
    for (int e = 0; e < 8; ++e) l[e] = a[e] + gb[e];
    float mx = l[0];
#pragma unroll
    for (int e = 1; e < 8; ++e) mx = fmaxf(mx, l[e]);
    float p[8], Z = 0.f;
#pragma unroll
    for (int e = 0; e < 8; ++e) { p[e] = expf(l[e] - mx); Z += p[e]; }
#pragma unroll
    for (int e = 0; e < 8; ++e) p[e] /= Z;

    int e0 = 0; float v0 = p[0];
#pragma unroll
    for (int e = 1; e < 8; ++e) if (p[e] > v0) { v0 = p[e]; e0 = e; }
    int e1 = -1; float v1 = -1.f;
#pragma unroll
    for (int e = 0; e < 8; ++e) if (e != e0 && p[e] > v1) { v1 = p[e]; e1 = e; }
    float denom = v0 + v1 + 1e-9f;
    float w0 = v0 / denom, w1 = v1 / denom;

    if (lane == 0) {
        int p0 = atomicAdd(&counts[e0], 1);
        int p1 = atomicAdd(&counts[e1], 1);
        lists[e0 * T_TOK + p0] = t;
        lists[e1 * T_TOK + p1] = t;
        tok_e[2 * t] = e0;  tok_e[2 * t + 1] = e1;
        tok_pos[2 * t] = p0; tok_pos[2 * t + 1] = p1;
        tok_w[2 * t] = w0;  tok_w[2 * t + 1] = w1;
    }
}

// ---------------------------------------------------------------- prefix
__global__ void k_prefix(const int* counts, int* offsets) {
    if (threadIdx.x == 0) {
        int o = 0;
        for (int e = 0; e < NE; ++e) { offsets[e] = o; o += counts[e]; }
        offsets[NE] = o;
    }
}

// ---------------------------------------------------------------- cast x -> bf16 dense
__global__ __launch_bounds__(256) void k_castx(const float* __restrict__ x,
                                               u16* __restrict__ xb)
{
    int i = (blockIdx.x * 256 + threadIdx.x) * 8;
    float4 a = *(const float4*)(x + i), b = *(const float4*)(x + i + 4);
    u16 t[8] = { f2bf(a.x), f2bf(a.y), f2bf(a.z), f2bf(a.w),
                 f2bf(b.x), f2bf(b.y), f2bf(b.z), f2bf(b.w) };
    *(bf16x8*)&xb[i] = *(bf16x8*)t;
}

// ---------------------------------------------------------------- transpose-cast weights
// src f32 [z][K][N] tilewise -> dst bf16 [z][N][K]
__global__ __launch_bounds__(256) void k_transcast(
    const float* __restrict__ src, u16* __restrict__ dst, int K, int N)
{
    src += (size_t)blockIdx.z * K * N;
    dst += (size_t)blockIdx.z * N * K;
    __shared__ float ls[64][33];
    int t = threadIdx.x;
    int k0 = blockIdx.y * 64, n0 = blockIdx.x * 32;
    {
        int kr = t >> 2, ng = (t & 3) * 8;
        const float* s = src + (size_t)(k0 + kr) * N + n0 + ng;
        float4 v0 = *(const float4*)s, v1 = *(const float4*)(s + 4);
        ls[kr][ng + 0] = v0.x; ls[kr][ng + 1] = v0.y; ls[kr][ng + 2] = v0.z; ls[kr][ng + 3] = v0.w;
        ls[kr][ng + 4] = v1.x; ls[kr][ng + 5] = v1.y; ls[kr][ng + 6] = v1.z; ls[kr][ng + 7] = v1.w;
    }
    __syncthreads();
    int n = t >> 3, kg = (t & 7) * 8;
    u16 o[8];
#pragma unroll
    for (int j = 0; j < 8; ++j) o[j] = f2bf(ls[kg + j][n]);
    *(bf16x8*)&dst[(size_t)(n0 + n) * K + k0 + kg] = *(bf16x8*)o;
}

// ---------------------------------------------------------------- grouped GEMM
// 128x128 tile, BK=32, 4 waves 2x2, mfma_f32_16x16x32_bf16.
// 3-buffer LDS pipeline, prefetch depth 2, counted s_waitcnt vmcnt(4) + raw
// s_barrier (T3+T4): prefetch loads stay in flight across barriers.
// T2 both-sides XOR swizzle (#21): linear LDS dest (global_load_lds), source
// quarter ^= (row>>1)&3, read quarter ^= (row>>1)&3 -> conflict-free b128.
// GEMM==1: A=xb gathered via lists (K=1024,N=4096), epi gelu->bf16 H.
// GEMM==2: A=H contiguous (K=4096,N=1024), epi +bias->f32 P.
template <int GEMM>
__global__ __launch_bounds__(256, 3)
void k_gemm(const u16* __restrict__ A, const u16* __restrict__ Bt,
            const float* __restrict__ be, const float* __restrict__ bsh,
            const int* __restrict__ counts, const int* __restrict__ offsets,
            const int* __restrict__ lists, void* __restrict__ Cg)
{
    constexpr int K = (GEMM == 1) ? D_DIM : I_DIM;
    constexpr int N = (GEMM == 1) ? I_DIM : D_DIM;

    const int e = blockIdx.z, mt = blockIdx.x, nt = blockIdx.y;
    const int cnt = counts[e];
    if (mt * 128 >= cnt) return;
    const int off = offsets[e];

    __shared__ __align__(16) u16 AsB[3][128 * BK];
    __shared__ __align__(16) u16 BsB[3][128 * BK];

    const int tid = threadIdx.x, w = tid >> 6, l = tid & 63;
    const int wu = __builtin_amdgcn_readfirstlane(w);   // uniform wave id
    const u16* Be = Bt + (size_t)e * N * K;

    // staged quarter swizzle: lane l covers local row (l>>2) (+16 per q),
    // LDS gets quarters in linear order; source quarter = (l&3)^((l>>3)&3).
    const int scol = (((l & 3) ^ ((l >> 3) & 3))) * 8;

    const u16* aptr[2];
    const u16* bptr[2];
#pragma unroll
    for (int q = 0; q < 2; ++q) {
        int row = mt * 128 + w * 32 + q * 16 + (l >> 2);
        int srow;
        if constexpr (GEMM == 1) {
            if (e == 8) srow = row;          // shared expert: token id == row
            else {
                int rc = row < cnt ? row : cnt - 1;
                srow = lists[e * T_TOK + rc];
            }
        } else {
            srow = off + row;                // contiguous H rows
        }
        aptr[q] = A + (size_t)srow * K + scol;
        bptr[q] = Be + (size_t)(nt * 128 + w * 32 + q * 16 + (l >> 2)) * K + scol;
    }

    const int lrow = l & 15;
    // read-side swizzled quarter (elements): ((l>>4) ^ ((lrow>>1)&3)) * 8
    const int rq = (((l >> 4) ^ ((lrow >> 1) & 3))) * 8;
    const int wr = w >> 1, wc = w & 1;

    f32x4 zero = {0.f, 0.f, 0.f, 0.f};
    f32x4 acc[4][4];
#pragma unroll
    for (int m = 0; m < 4; ++m)
#pragma unroll
        for (int n = 0; n < 4; ++n) acc[m][n] = zero;

    auto stage = [&](u16* As_, u16* Bs_, int ko) {
#pragma unroll
        for (int q = 0; q < 2; ++q) {
            gl16(aptr[q] + ko, As_ + wu * 1024 + q * 512);
            gl16(bptr[q] + ko, Bs_ + wu * 1024 + q * 512);
        }
    };
    auto compute = [&](const u16* As_, const u16* Bs_) {
        bf16x8 afr[4], bfr[4];
#pragma unroll
        for (int m = 0; m < 4; ++m)
            afr[m] = *(const bf16x8*)&As_[(wr * 64 + m * 16 + lrow) * BK + rq];
#pragma unroll
        for (int n = 0; n < 4; ++n)
            bfr[n] = *(const bf16x8*)&Bs_[(wc * 64 + n * 16 + lrow) * BK + rq];
#pragma unroll
        for (int m = 0; m < 4; ++m)
#pragma unroll
            for (int n = 0; n < 4; ++n)
                acc[m][n] = __builtin_amdgcn_mfma_f32_16x16x32_bf16(afr[m], bfr[n], acc[m][n], 0, 0, 0);
    };

    constexpr int nk = K / BK;               // 32 or 128
    u16 *a0 = AsB[0], *a1 = AsB[1], *a2 = AsB[2];
    u16 *b0 = BsB[0], *b1 = BsB[1], *b2 = BsB[2];

    stage(a0, b0, 0);
    stage(a1, b1, BK);
    for (int kt = 0; kt < nk - 2; ++kt) {
        asm volatile("s_waitcnt vmcnt(4)" ::: "memory");  // oldest stage landed
        __builtin_amdgcn_s_barrier();                     // all waves' too
        stage(a2, b2, (kt + 2) * BK);                     // refill consumed buf
        compute(a0, b0);
        u16* ta = a0; a0 = a1; a1 = a2; a2 = ta;          // rotate
        u16* tb = b0; b0 = b1; b1 = b2; b2 = tb;
    }
    asm volatile("s_waitcnt vmcnt(4)" ::: "memory");
    __builtin_amdgcn_s_barrier();
    compute(a0, b0);
    asm volatile("s_waitcnt vmcnt(0)" ::: "memory");
    __builtin_amdgcn_s_barrier();
    compute(a1, b1);

    // ---- epilogue.  D mapping: col = lane&15, row = (lane>>4)*4 + reg
    const float* bias = (e == 8) ? bsh : (be + (size_t)e * N);
#pragma unroll
    for (int m = 0; m < 4; ++m) {
        int pbase = mt * 128 + wr * 64 + m * 16 + (l >> 4) * 4;
#pragma unroll
        for (int n = 0; n < 4; ++n) {
            int gcol = nt * 128 + wc * 64 + n * 16 + (l & 15);
            float bv = bias[gcol];
#pragma unroll
            for (int r = 0; r < 4; ++r) {
                int pos = pbase + r;
                if (pos < cnt) {
                    float v = acc[m][n][r] + bv;
                    if constexpr (GEMM == 1)
                        ((u16*)Cg)[(size_t)(off + pos) * N + gcol] = f2bf(gelu_fast(v));
                    else
                        ((float*)Cg)[(size_t)(off + pos) * N + gcol] = v;
                }
            }
        }
    }
}

// ---------------------------------------------------------------- combine
__global__ __launch_bounds__(256) void k_combine(
    const float* __restrict__ x, const float* __restrict__ P,
    const int* __restrict__ offsets, const int* __restrict__ tok_e,
    const int* __restrict__ tok_pos, const float* __restrict__ tok_w,
    float* __restrict__ out)
{
    int t = blockIdx.x;
    int e0 = tok_e[2 * t], e1 = tok_e[2 * t + 1];
    int r0 = offsets[e0] + tok_pos[2 * t];
    int r1 = offsets[e1] + tok_pos[2 * t + 1];
    int rs = offsets[8] + t;
    float w0 = tok_w[2 * t], w1 = tok_w[2 * t + 1];
    int i = threadIdx.x * 4;

    float4 xv = *(const float4*)(x + (size_t)t * D_DIM + i);
    float4 ps = *(const float4*)(P + (size_t)rs * D_DIM + i);
    float4 p0 = *(const float4*)(P + (size_t)r0 * D_DIM + i);
    float4 p1 = *(const float4*)(P + (size_t)r1 * D_DIM + i);
    float4 o;
    o.x = xv.x + ps.x + w0 * p0.x + w1 * p1.x;
    o.y = xv.y + ps.y + w0 * p0.y + w1 * p1.y;
    o.z = xv.z + ps.z + w0 * p0.z + w1 * p1.z;
    o.w = xv.w + ps.w + w0 * p0.w + w1 * p1.w;
    *(float4*)(out + (size_t)t * D_DIM + i) = o;
}

// ---------------------------------------------------------------- launch
extern "C" void kernel_launch(void* const* d_in, const int* in_sizes, int n_in,
                              void* d_out, int out_size, void* d_ws, size_t ws_size,
                              hipStream_t stream)
{
    const float* x   = (const float*)d_in[0];
    const float* gw  = (const float*)d_in[1];
    const float* gb  = (const float*)d_in[2];
    const float* sw1 = (const float*)d_in[3];
    const float* sb1 = (const float*)d_in[4];
    const float* sw2 = (const float*)d_in[5];
    const float* sb2 = (const float*)d_in[6];
    const float* ew1 = (const float*)d_in[7];
    const float* eb1 = (const float*)d_in[8];
    const float* ew2 = (const float*)d_in[9];
    const float* eb2 = (const float*)d_in[10];

    char* w = (char*)d_ws;
    int* counts  = (int*)w;                       // 16 ints
    int* offsets = (int*)(w + 64);                // 16 ints
    int* tok_e   = (int*)(w + 128);               // 2T ints
    int* tok_pos = tok_e + 2 * T_TOK;             // 2T ints
    float* tok_w = (float*)(tok_pos + 2 * T_TOK); // 2T floats
    int* lists   = (int*)(tok_w + 2 * T_TOK);     // 8T ints (routed only)

    size_t o = (size_t)1 << 20;                   // 1MB: small buffers above
    u16* xb  = (u16*)(w + o);                     // 4096 x 1024 bf16 (8MB)
    o += (size_t)T_TOK * D_DIM * 2;
    u16* H   = (u16*)(w + o);                     // 12288 x 4096 bf16 (96MB)
    o += (size_t)3 * T_TOK * I_DIM * 2;
    u16* Wt  = (u16*)(w + o);                     // 9 x 4096 x 1024 bf16 (72MB), W1t then W2t
    o += (size_t)NE * I_DIM * D_DIM * 2;
    float* P = (float*)(w + o);                   // 12288 x 1024 f32 (48MB)

    k_init<<<1, 64, 0, stream>>>(counts);

    // W1^T: [K=1024][N=4096] -> bf16 [4096][1024]
    k_transcast<<<dim3(I_DIM / 32, D_DIM / 64, 8), 256, 0, stream>>>(ew1, Wt, D_DIM, I_DIM);
    k_transcast<<<dim3(I_DIM / 32, D_DIM / 64, 1), 256, 0, stream>>>(
        sw1, Wt + (size_t)8 * I_DIM * D_DIM, D_DIM, I_DIM);
    k_castx<<<T_TOK * D_DIM / (256 * 8), 256, 0, stream>>>(x, xb);

    k_router<<<T_TOK / 4, 256, 0, stream>>>(x, gw, gb, counts, lists, tok_e, tok_pos, tok_w);
    k_prefix<<<1, 64, 0, stream>>>(counts, offsets);

    // GEMM1: H = gelu(Xg @ W1 + b1), N = I
    k_gemm<1><<<dim3(32, I_DIM / 128, NE), 256, 0, stream>>>(
        xb, Wt, eb1, sb1, counts, offsets, lists, (void*)H);

    // W2^T: [K=4096][N=1024] -> bf16 [1024][4096]  (aliases W1t region; stream-ordered)
    k_transcast<<<dim3(D_DIM / 32, I_DIM / 64, 8), 256, 0, stream>>>(ew2, Wt, I_DIM, D_DIM);
    k_transcast<<<dim3(D_DIM / 32, I_DIM / 64, 1), 256, 0, stream>>>(
        sw2, Wt + (size_t)8 * I_DIM * D_DIM, I_DIM, D_DIM);

    // GEMM2: P = H @ W2 + b2, N = D
    k_gemm<2><<<dim3(32, D_DIM / 128, NE), 256, 0, stream>>>(
        H, Wt, eb2, sb2, counts, offsets, lists, (void*)P);

    k_combine<<<T_TOK, 256, 0, stream>>>(x, P, offsets, tok_e, tok_pos, tok_w, (float*)d_out);
}